// Round 1
// baseline (305.591 us; speedup 1.0000x reference)
//
#include <hip/hip_runtime.h>
#include <cstdint>

// Problem constants (from reference): B=4, Z=32, Y=512, X=512, R=1, C=16
static constexpr int Z_ = 32, Y_ = 512, X_ = 512;

__device__ __forceinline__ uint32_t ht_slot0(int key, int ht_log) {
    return ((uint32_t)key * 2654435761u) >> (32 - ht_log);
}

// ws layout: [64 bytes: acc[0..3] = occ_sum, off_sum, feat_sum, cnt][table: 2*ht_size int32]
__global__ void init_ws_kernel(int* __restrict__ table, uint32_t ht_size, float* __restrict__ acc) {
    uint32_t i = blockIdx.x * blockDim.x + threadIdx.x;
    uint32_t stride = gridDim.x * blockDim.x;
    for (uint32_t s = i; s < ht_size; s += stride) {
        table[2*s]     = -1;          // empty key
        table[2*s + 1] = 0x7FFFFFFF;  // +inf for atomicMin
    }
    if (i < 4) acc[i] = 0.0f;
}

__global__ void build_kernel(const int* __restrict__ lidar_idx, int Nl,
                             int* __restrict__ table, uint32_t ht_mask, int ht_log) {
    int i = blockIdx.x * blockDim.x + threadIdx.x;
    if (i >= Nl) return;
    int b = lidar_idx[4*i + 0];
    int z = lidar_idx[4*i + 1];
    int y = lidar_idx[4*i + 2];
    int x = lidar_idx[4*i + 3];
    int key = ((b*Z_ + z)*Y_ + y)*X_ + x;
    uint32_t slot = ht_slot0(key, ht_log);
    for (;;) {
        int prev = atomicCAS(&table[2*slot], -1, key);
        if (prev == -1 || prev == key) {
            // duplicate hashes: stable argsort + searchsorted-left == min original index
            atomicMin(&table[2*slot + 1], i);
            return;
        }
        slot = (slot + 1) & ht_mask;
    }
}

__global__ void match_kernel(const float* __restrict__ pred_feat,
                             const float* __restrict__ pred_occ,
                             const float* __restrict__ lidar_feat,
                             const int* __restrict__ radar_idx,
                             const int* __restrict__ table,
                             uint32_t ht_mask, int ht_log,
                             int Nr, float* __restrict__ acc) {
    int i = blockIdx.x * blockDim.x + threadIdx.x;
    float occ_t = 0.f, off_t = 0.f, feat_t = 0.f, cnt_t = 0.f;
    if (i < Nr) {
        int b = radar_idx[4*i + 0];
        int z = radar_idx[4*i + 1];
        int y = radar_idx[4*i + 2];
        int x = radar_idx[4*i + 3];
        int best_d = 1 << 30;
        int best_row = -1;
        int bz = 0, by = 0, bx = 0;
        // meshgrid('ij') order: dz slowest, dx fastest -> first-occurrence argmin
        #pragma unroll
        for (int dz = -1; dz <= 1; ++dz) {
            #pragma unroll
            for (int dy = -1; dy <= 1; ++dy) {
                #pragma unroll
                for (int dx = -1; dx <= 1; ++dx) {
                    int d = abs(dz) + abs(dy) + abs(dx);
                    if (d >= best_d) continue;  // strict <: argmin keeps FIRST minimum
                    int zz = min(max(z + dz, 0), Z_ - 1);
                    int yy = min(max(y + dy, 0), Y_ - 1);
                    int xx = min(max(x + dx, 0), X_ - 1);
                    int key = ((b*Z_ + zz)*Y_ + yy)*X_ + xx;
                    uint32_t slot = ht_slot0(key, ht_log);
                    int row = -1;
                    for (;;) {
                        int k2 = table[2*slot];
                        if (k2 == key) { row = table[2*slot + 1]; break; }
                        if (k2 == -1) break;
                        slot = (slot + 1) & ht_mask;
                    }
                    if (row >= 0) { best_d = d; best_row = row; bz = zz; by = yy; bx = xx; }
                }
            }
        }
        float o = pred_occ[i];
        float t = (best_row >= 0) ? 1.f : 0.f;
        // stable softplus: max(o,0) + log1p(exp(-|o|))
        float sp = fmaxf(o, 0.f) + log1pf(expf(-fabsf(o)));
        occ_t = sp - o * t;
        if (best_row >= 0) {
            cnt_t = 1.f;
            float4 pf = reinterpret_cast<const float4*>(pred_feat)[i];
            float gd0 = (float)(bz - z), gd1 = (float)(by - y), gd2 = (float)(bx - x);
            float p[3] = { pf.x, pf.y, pf.z };
            float g[3] = { gd0, gd1, gd2 };
            #pragma unroll
            for (int j = 0; j < 3; ++j) {
                float dd = p[j] - g[j];
                float ad = fabsf(dd);
                off_t += (ad < 1.f) ? 0.5f * dd * dd : ad - 0.5f;
            }
            float gf = lidar_feat[16 * best_row];  // only column 0 is consumed
            feat_t = fabsf(pf.w - gf);
        }
    }
    // wave-64 shuffle reduction, then one atomic per wave per accumulator
    #pragma unroll
    for (int off = 32; off >= 1; off >>= 1) {
        occ_t  += __shfl_down(occ_t,  off, 64);
        off_t  += __shfl_down(off_t,  off, 64);
        feat_t += __shfl_down(feat_t, off, 64);
        cnt_t  += __shfl_down(cnt_t,  off, 64);
    }
    if ((threadIdx.x & 63) == 0) {
        atomicAdd(&acc[0], occ_t);
        atomicAdd(&acc[1], off_t);
        atomicAdd(&acc[2], feat_t);
        atomicAdd(&acc[3], cnt_t);
    }
}

__global__ void finalize_kernel(const float* __restrict__ acc, int Nr, float* __restrict__ out) {
    float occ  = acc[0] / (float)Nr;
    float cnt  = acc[3];
    float offl = acc[1] / fmaxf(cnt * 3.f, 1.f);
    float feat = acc[2] / fmaxf(cnt, 1.f);
    out[0] = 0.2f * occ + offl + feat;
}

extern "C" void kernel_launch(void* const* d_in, const int* in_sizes, int n_in,
                              void* d_out, int out_size, void* d_ws, size_t ws_size,
                              hipStream_t stream) {
    const float* pred_feat  = (const float*)d_in[0];
    const float* pred_occ   = (const float*)d_in[1];
    const float* lidar_feat = (const float*)d_in[2];
    const int*   radar_idx  = (const int*)d_in[3];
    const int*   lidar_idx  = (const int*)d_in[4];
    int Nr = in_sizes[1];        // pred_occ is (Nr, 1)
    int Nl = in_sizes[2] / 16;   // lidar_features is (Nl, 16)

    // hash table sizing: prefer 2^20 slots (8 MiB, ~0.4 load), shrink if ws is tight
    int ht_log = 20;
    while (ht_log > 19 && (size_t)(64 + 8ull * (1ull << ht_log)) > ws_size) --ht_log;
    uint32_t ht_size = 1u << ht_log;
    uint32_t ht_mask = ht_size - 1;

    float* acc  = (float*)d_ws;
    int*   table = (int*)((char*)d_ws + 64);

    hipLaunchKernelGGL(init_ws_kernel, dim3(2048), dim3(256), 0, stream, table, ht_size, acc);
    hipLaunchKernelGGL(build_kernel, dim3((Nl + 255) / 256), dim3(256), 0, stream,
                       lidar_idx, Nl, table, ht_mask, ht_log);
    hipLaunchKernelGGL(match_kernel, dim3((Nr + 255) / 256), dim3(256), 0, stream,
                       pred_feat, pred_occ, lidar_feat, radar_idx, table, ht_mask, ht_log, Nr, acc);
    hipLaunchKernelGGL(finalize_kernel, dim3(1), dim3(1), 0, stream, acc, Nr, (float*)d_out);
}

// Round 2
// 180.947 us; speedup vs baseline: 1.6888x; 1.6888x over previous
//
#include <hip/hip_runtime.h>
#include <cstdint>
#include <climits>

// Problem constants (from reference): B=4, Z=32, Y=512, X=512, R=1, C=16
static constexpr int Z_ = 32, Y_ = 512, X_ = 512;

__device__ __forceinline__ uint32_t ht_slot0(int key, int ht_log) {
    return ((uint32_t)key * 2654435761u) >> (32 - ht_log);
}

// ws layout:
//   [0, 256)        : acc[0..3] at 64B stride (occ, off, feat, cnt) -> 4 TCC channels
//   [256, 256+4S)   : keys (int32, -1 = empty)   S = ht_size
//   [256+4S, ..+8S) : vals (int32, min lidar row; init 0x7F7F7F7F)

__global__ void build_kernel(const int* __restrict__ lidar_idx, int Nl,
                             int* __restrict__ keys, int* __restrict__ vals,
                             uint32_t ht_mask, int ht_log) {
    int i = blockIdx.x * blockDim.x + threadIdx.x;
    if (i >= Nl) return;
    int4 li = reinterpret_cast<const int4*>(lidar_idx)[i];
    int key = ((li.x * Z_ + li.y) * Y_ + li.z) * X_ + li.w;
    uint32_t slot = ht_slot0(key, ht_log);
    for (;;) {
        int prev = atomicCAS(&keys[slot], -1, key);
        if (prev == -1 || prev == key) {
            // duplicate hashes: stable argsort + searchsorted-left == min original index
            atomicMin(&vals[slot], i);
            return;
        }
        slot = (slot + 1) & ht_mask;
    }
}

// 32 lanes per radar point: lane k handles neighbor offset k (k<27), one probe each.
// Packed candidate = (dL1<<5)|k; min-reduce == first-occurrence argmin of reference.
__global__ __launch_bounds__(256) void match_kernel(
        const float* __restrict__ pred_feat,
        const float* __restrict__ pred_occ,
        const float* __restrict__ lidar_feat,
        const int* __restrict__ radar_idx,
        const int* __restrict__ keys, const int* __restrict__ vals,
        uint32_t ht_mask, int ht_log,
        int Nr, float* __restrict__ acc) {
    const int sub    = threadIdx.x & 31;   // lane within 32-group = offset index k
    const int halfId = threadIdx.x >> 5;   // 0..7: which radar point in the block slice
    const int k = sub;
    const int dz = k / 9 - 1;
    const int rem = k % 9;
    const int dy = rem / 3 - 1;
    const int dx = rem % 3 - 1;
    const int dl1 = abs(dz) + abs(dy) + abs(dx);
    const bool act = (k < 27);

    float occ_a = 0.f, off_a = 0.f, feat_a = 0.f, cnt_a = 0.f;

    for (int base = blockIdx.x * 8; base < Nr; base += gridDim.x * 8) {
        int r = base + halfId;
        if (r < Nr) {
            int4 ri = reinterpret_cast<const int4*>(radar_idx)[r];  // broadcast within group
            int b = ri.x, z = ri.y, y = ri.z, x = ri.w;
            int packed = INT_MAX;
            int row = -1;
            if (act) {
                int zz = min(max(z + dz, 0), Z_ - 1);
                int yy = min(max(y + dy, 0), Y_ - 1);
                int xx = min(max(x + dx, 0), X_ - 1);
                int key = ((b * Z_ + zz) * Y_ + yy) * X_ + xx;
                uint32_t slot = ht_slot0(key, ht_log);
                for (;;) {
                    int k2 = keys[slot];
                    if (k2 == key) { row = vals[slot]; packed = (dl1 << 5) | k; break; }
                    if (k2 == -1) break;
                    slot = (slot + 1) & ht_mask;
                }
            }
            // min-reduce within the 32-lane group
            #pragma unroll
            for (int o = 16; o >= 1; o >>= 1)
                packed = min(packed, __shfl_xor(packed, o, 32));
            int wk    = packed & 31;
            int row_w = __shfl(row, wk, 32);
            if (sub == 0) {
                float o = pred_occ[r];
                bool m = (packed != INT_MAX);
                // stable softplus
                float sp = fmaxf(o, 0.f) + log1pf(expf(-fabsf(o)));
                occ_a += sp - (m ? o : 0.f);
                if (m) {
                    cnt_a += 1.f;
                    float4 pf = reinterpret_cast<const float4*>(pred_feat)[r];
                    int wdz = wk / 9 - 1, wrem = wk % 9;
                    int wdy = wrem / 3 - 1, wdx = wrem % 3 - 1;
                    float g0 = (float)(min(max(z + wdz, 0), Z_ - 1) - z);
                    float g1 = (float)(min(max(y + wdy, 0), Y_ - 1) - y);
                    float g2 = (float)(min(max(x + wdx, 0), X_ - 1) - x);
                    float p[3] = { pf.x, pf.y, pf.z };
                    float g[3] = { g0, g1, g2 };
                    #pragma unroll
                    for (int j = 0; j < 3; ++j) {
                        float dd = p[j] - g[j];
                        float ad = fabsf(dd);
                        off_a += (ad < 1.f) ? 0.5f * dd * dd : ad - 0.5f;
                    }
                    feat_a += fabsf(pf.w - lidar_feat[16 * row_w]);
                }
            }
        }
    }

    // wave-64 butterfly (only sub==0 lanes hold nonzero partials) then block LDS reduce
    #pragma unroll
    for (int o = 32; o >= 1; o >>= 1) {
        occ_a  += __shfl_xor(occ_a,  o, 64);
        off_a  += __shfl_xor(off_a,  o, 64);
        feat_a += __shfl_xor(feat_a, o, 64);
        cnt_a  += __shfl_xor(cnt_a,  o, 64);
    }
    __shared__ float red[4][4];
    int wid = threadIdx.x >> 6;
    if ((threadIdx.x & 63) == 0) {
        red[wid][0] = occ_a; red[wid][1] = off_a;
        red[wid][2] = feat_a; red[wid][3] = cnt_a;
    }
    __syncthreads();
    if (threadIdx.x == 0) {
        float s0 = 0.f, s1 = 0.f, s2 = 0.f, s3 = 0.f;
        #pragma unroll
        for (int w = 0; w < 4; ++w) {
            s0 += red[w][0]; s1 += red[w][1]; s2 += red[w][2]; s3 += red[w][3];
        }
        atomicAdd(&acc[0],  s0);
        atomicAdd(&acc[16], s1);
        atomicAdd(&acc[32], s2);
        atomicAdd(&acc[48], s3);
    }
}

__global__ void finalize_kernel(const float* __restrict__ acc, int Nr, float* __restrict__ out) {
    float occ  = acc[0] / (float)Nr;
    float cnt  = acc[48];
    float offl = acc[16] / fmaxf(cnt * 3.f, 1.f);
    float feat = acc[32] / fmaxf(cnt, 1.f);
    out[0] = 0.2f * occ + offl + feat;
}

extern "C" void kernel_launch(void* const* d_in, const int* in_sizes, int n_in,
                              void* d_out, int out_size, void* d_ws, size_t ws_size,
                              hipStream_t stream) {
    const float* pred_feat  = (const float*)d_in[0];
    const float* pred_occ   = (const float*)d_in[1];
    const float* lidar_feat = (const float*)d_in[2];
    const int*   radar_idx  = (const int*)d_in[3];
    const int*   lidar_idx  = (const int*)d_in[4];
    int Nr = in_sizes[1];        // pred_occ is (Nr, 1)
    int Nl = in_sizes[2] / 16;   // lidar_features is (Nl, 16)

    int ht_log = 20;
    while (ht_log > 19 && (size_t)(256 + 8ull * (1ull << ht_log)) > ws_size) --ht_log;
    uint32_t ht_size = 1u << ht_log;
    uint32_t ht_mask = ht_size - 1;

    float* acc  = (float*)d_ws;
    int*   keys = (int*)((char*)d_ws + 256);
    int*   vals = keys + ht_size;

    hipMemsetAsync(acc,  0,    256,           stream);
    hipMemsetAsync(keys, 0xFF, 4ull * ht_size, stream);  // -1 = empty
    hipMemsetAsync(vals, 0x7F, 4ull * ht_size, stream);  // 0x7F7F7F7F = +inf sentinel

    hipLaunchKernelGGL(build_kernel, dim3((Nl + 255) / 256), dim3(256), 0, stream,
                       lidar_idx, Nl, keys, vals, ht_mask, ht_log);
    hipLaunchKernelGGL(match_kernel, dim3(2048), dim3(256), 0, stream,
                       pred_feat, pred_occ, lidar_feat, radar_idx, keys, vals,
                       ht_mask, ht_log, Nr, acc);
    hipLaunchKernelGGL(finalize_kernel, dim3(1), dim3(1), 0, stream, acc, Nr, (float*)d_out);
}

// Round 3
// 152.301 us; speedup vs baseline: 2.0065x; 1.1881x over previous
//
#include <hip/hip_runtime.h>
#include <cstdint>
#include <climits>

// Problem constants (from reference): B=4, Z=32, Y=512, X=512, R=1, C=16
static constexpr int Z_ = 32, Y_ = 512, X_ = 512;

__device__ __forceinline__ uint32_t ht_slot0(int key, int ht_log) {
    return ((uint32_t)key * 2654435761u) >> (32 - ht_log);
}

// ws layout:
//   [0, 256)             : acc[0..3] at 64B stride (occ, off, feat, cnt)
//   [256, 256+4S)        : keys (int32, -1 = empty)      S = ht_size
//   [256+4S, 256+8S)     : vals (int32, min lidar row; init 0x7F7F7F7F)
//   [256+8S, 256+8S+4Nr) : res  (int32 per radar: -1 or (row<<5)|k)

__global__ void build_kernel(const int* __restrict__ lidar_idx, int Nl,
                             int* __restrict__ keys, int* __restrict__ vals,
                             uint32_t ht_mask, int ht_log) {
    int i = blockIdx.x * blockDim.x + threadIdx.x;
    if (i >= Nl) return;
    int4 li = reinterpret_cast<const int4*>(lidar_idx)[i];
    int key = ((li.x * Z_ + li.y) * Y_ + li.z) * X_ + li.w;
    uint32_t slot = ht_slot0(key, ht_log);
    for (;;) {
        int prev = atomicCAS(&keys[slot], -1, key);
        if (prev == -1 || prev == key) {
            // duplicate hashes: stable argsort + searchsorted-left == min original index
            atomicMin(&vals[slot], i);
            return;
        }
        slot = (slot + 1) & ht_mask;
    }
}

// Kernel A: pure matching. 32 lanes per radar point, lane k = offset k (k<27).
// Packed candidate = (dL1<<5)|k; min == first-occurrence argmin of the reference.
// After the reduce, the WINNING lane writes its own row (no broadcast needed).
__global__ __launch_bounds__(256) void match_kernel(
        const int* __restrict__ radar_idx,
        const int* __restrict__ keys, const int* __restrict__ vals,
        uint32_t ht_mask, int ht_log,
        int Nr, int* __restrict__ res) {
    const int sub = threadIdx.x & 31;   // offset index k
    const int grp = threadIdx.x >> 5;   // 0..7: radar point within block slice
    const int k = sub;
    const int dz = k / 9 - 1;
    const int rem = k % 9;
    const int dy = rem / 3 - 1;
    const int dx = rem % 3 - 1;
    const int dl1 = abs(dz) + abs(dy) + abs(dx);
    const bool act = (k < 27);

    for (int base = blockIdx.x * 8; base < Nr; base += gridDim.x * 8) {
        int r = base + grp;
        if (r < Nr) {
            int4 ri = reinterpret_cast<const int4*>(radar_idx)[r];
            int packed = INT_MAX;
            int row = 0;
            if (act) {
                int zz = min(max(ri.y + dz, 0), Z_ - 1);
                int yy = min(max(ri.z + dy, 0), Y_ - 1);
                int xx = min(max(ri.w + dx, 0), X_ - 1);
                int key = ((ri.x * Z_ + zz) * Y_ + yy) * X_ + xx;
                uint32_t slot = ht_slot0(key, ht_log);
                for (;;) {
                    uint32_t s1 = (slot + 1) & ht_mask;
                    int ka = keys[slot];    // two independent probes issue together
                    int kb = keys[s1];
                    if (ka == key) { row = vals[slot]; packed = (dl1 << 5) | k; break; }
                    if (ka == -1) break;
                    if (kb == key) { row = vals[s1]; packed = (dl1 << 5) | k; break; }
                    if (kb == -1) break;
                    slot = (slot + 2) & ht_mask;
                }
            }
            #pragma unroll
            for (int o = 16; o >= 1; o >>= 1)
                packed = min(packed, __shfl_xor(packed, o, 32));
            // exactly one writer: winning lane (packed&31); if no hit, lane 31 writes -1
            if (sub == (packed & 31))
                res[r] = (packed == INT_MAX) ? -1 : ((row << 5) | (packed & 31));
        }
    }
}

// Kernel B: vectorized loss. One lane per radar point, fully coalesced.
__global__ __launch_bounds__(256) void loss_kernel(
        const float* __restrict__ pred_feat,
        const float* __restrict__ pred_occ,
        const float* __restrict__ lidar_feat,
        const int* __restrict__ radar_idx,
        const int* __restrict__ res,
        int Nr, float* __restrict__ acc) {
    float occ_a = 0.f, off_a = 0.f, feat_a = 0.f, cnt_a = 0.f;
    for (int r = blockIdx.x * blockDim.x + threadIdx.x; r < Nr;
         r += gridDim.x * blockDim.x) {
        int rv = res[r];
        float o = pred_occ[r];
        // stable softplus: max(o,0) + log1p(exp(-|o|))
        float sp = fmaxf(o, 0.f) + log1pf(expf(-fabsf(o)));
        bool m = (rv >= 0);
        occ_a += sp - (m ? o : 0.f);
        if (m) {
            cnt_a += 1.f;
            float4 pf = reinterpret_cast<const float4*>(pred_feat)[r];
            int4 ri = reinterpret_cast<const int4*>(radar_idx)[r];
            int wk = rv & 31;
            int row = rv >> 5;
            int wdz = wk / 9 - 1;
            int wrem = wk % 9;
            int wdy = wrem / 3 - 1;
            int wdx = wrem % 3 - 1;
            float g0 = (float)(min(max(ri.y + wdz, 0), Z_ - 1) - ri.y);
            float g1 = (float)(min(max(ri.z + wdy, 0), Y_ - 1) - ri.z);
            float g2 = (float)(min(max(ri.w + wdx, 0), X_ - 1) - ri.w);
            float p[3] = { pf.x, pf.y, pf.z };
            float g[3] = { g0, g1, g2 };
            #pragma unroll
            for (int j = 0; j < 3; ++j) {
                float dd = p[j] - g[j];
                float ad = fabsf(dd);
                off_a += (ad < 1.f) ? 0.5f * dd * dd : ad - 0.5f;
            }
            feat_a += fabsf(pf.w - lidar_feat[16 * row]);
        }
    }
    // wave-64 butterfly, then tiny LDS block reduce, then 4 atomics per block
    #pragma unroll
    for (int o = 32; o >= 1; o >>= 1) {
        occ_a  += __shfl_xor(occ_a,  o, 64);
        off_a  += __shfl_xor(off_a,  o, 64);
        feat_a += __shfl_xor(feat_a, o, 64);
        cnt_a  += __shfl_xor(cnt_a,  o, 64);
    }
    __shared__ float red[4][4];
    int wid = threadIdx.x >> 6;
    if ((threadIdx.x & 63) == 0) {
        red[wid][0] = occ_a; red[wid][1] = off_a;
        red[wid][2] = feat_a; red[wid][3] = cnt_a;
    }
    __syncthreads();
    if (threadIdx.x == 0) {
        float s0 = 0.f, s1 = 0.f, s2 = 0.f, s3 = 0.f;
        #pragma unroll
        for (int w = 0; w < 4; ++w) {
            s0 += red[w][0]; s1 += red[w][1]; s2 += red[w][2]; s3 += red[w][3];
        }
        atomicAdd(&acc[0],  s0);
        atomicAdd(&acc[16], s1);
        atomicAdd(&acc[32], s2);
        atomicAdd(&acc[48], s3);
    }
}

__global__ void finalize_kernel(const float* __restrict__ acc, int Nr, float* __restrict__ out) {
    float occ  = acc[0] / (float)Nr;
    float cnt  = acc[48];
    float offl = acc[16] / fmaxf(cnt * 3.f, 1.f);
    float feat = acc[32] / fmaxf(cnt, 1.f);
    out[0] = 0.2f * occ + offl + feat;
}

extern "C" void kernel_launch(void* const* d_in, const int* in_sizes, int n_in,
                              void* d_out, int out_size, void* d_ws, size_t ws_size,
                              hipStream_t stream) {
    const float* pred_feat  = (const float*)d_in[0];
    const float* pred_occ   = (const float*)d_in[1];
    const float* lidar_feat = (const float*)d_in[2];
    const int*   radar_idx  = (const int*)d_in[3];
    const int*   lidar_idx  = (const int*)d_in[4];
    int Nr = in_sizes[1];        // pred_occ is (Nr, 1)
    int Nl = in_sizes[2] / 16;   // lidar_features is (Nl, 16)

    // size table to fit ws: need 256 + 8*S + 4*Nr
    int ht_log = 20;
    while (ht_log > 17 &&
           (size_t)(256 + 8ull * (1ull << ht_log) + 4ull * (size_t)Nr) > ws_size)
        --ht_log;
    uint32_t ht_size = 1u << ht_log;
    uint32_t ht_mask = ht_size - 1;

    float* acc  = (float*)d_ws;
    int*   keys = (int*)((char*)d_ws + 256);
    int*   vals = keys + ht_size;
    int*   res  = vals + ht_size;

    hipMemsetAsync(acc,  0,    256,            stream);
    hipMemsetAsync(keys, 0xFF, 4ull * ht_size, stream);  // -1 = empty
    hipMemsetAsync(vals, 0x7F, 4ull * ht_size, stream);  // +inf sentinel for atomicMin

    hipLaunchKernelGGL(build_kernel, dim3((Nl + 255) / 256), dim3(256), 0, stream,
                       lidar_idx, Nl, keys, vals, ht_mask, ht_log);
    hipLaunchKernelGGL(match_kernel, dim3(2048), dim3(256), 0, stream,
                       radar_idx, keys, vals, ht_mask, ht_log, Nr, res);
    hipLaunchKernelGGL(loss_kernel, dim3((Nr + 255) / 256), dim3(256), 0, stream,
                       pred_feat, pred_occ, lidar_feat, radar_idx, res, Nr, acc);
    hipLaunchKernelGGL(finalize_kernel, dim3(1), dim3(1), 0, stream, acc, Nr, (float*)d_out);
}

// Round 4
// 112.051 us; speedup vs baseline: 2.7273x; 1.3592x over previous
//
#include <hip/hip_runtime.h>
#include <cstdint>
#include <climits>

// Problem constants (from reference): B=4, Z=32, Y=512, X=512, R=1, C=16
static constexpr int Z_ = 32, Y_ = 512, X_ = 512;
static constexpr int ROW_WORDS = X_ / 32;               // 16 u32 words per (b,z,y) row
static constexpr size_t BITMAP_WORDS = 4ull * Z_ * Y_ * (X_ / 32);  // 1M words = 4 MiB

__device__ __forceinline__ uint32_t ht_slot0(int key, int ht_log) {
    return ((uint32_t)key * 2654435761u) >> (32 - ht_log);
}

// dL1 priority masks over k = (dz+1)*9 + (dy+1)*3 + (dx+1), k in [0,27)
static constexpr uint32_t M0 = 1u << 13;
static constexpr uint32_t M1 = (1u<<4)|(1u<<10)|(1u<<12)|(1u<<14)|(1u<<16)|(1u<<22);
static constexpr uint32_t M3 = (1u<<0)|(1u<<2)|(1u<<6)|(1u<<8)|(1u<<18)|(1u<<20)|(1u<<24)|(1u<<26);
static constexpr uint32_t MALL = (1u<<27) - 1;
static constexpr uint32_t M2 = MALL & ~(M0|M1|M3);

// ws layout:
//   [0, 256)                  : acc[0..3] at 64B stride (occ, off, feat, cnt)   (memset 0 with bitmap)
//   [256, 256+4MiB)           : occupancy bitmap (1 bit per voxel)
//   [256+4MiB, +4S)           : keys (int32, -1 = empty)
//   [.., +4S)                 : vals (uint32, min lidar row; 0xFFFFFFFF = +inf)

__global__ void build_kernel(const int* __restrict__ lidar_idx, int Nl,
                             uint32_t* __restrict__ bitmap,
                             int* __restrict__ keys, unsigned int* __restrict__ vals,
                             uint32_t ht_mask, int ht_log) {
    int i = blockIdx.x * blockDim.x + threadIdx.x;
    if (i >= Nl) return;
    int4 li = reinterpret_cast<const int4*>(lidar_idx)[i];
    int key = ((li.x * Z_ + li.y) * Y_ + li.z) * X_ + li.w;
    uint32_t slot = ht_slot0(key, ht_log);
    for (;;) {
        int prev = atomicCAS(&keys[slot], -1, key);
        if (prev == -1) {
            // first claimant of this voxel also publishes the bitmap bit
            atomicOr(&bitmap[(uint32_t)key >> 5], 1u << (key & 31));
            atomicMin(&vals[slot], (unsigned int)i);
            return;
        }
        if (prev == key) {
            // duplicates: stable argsort + searchsorted-left == min original index
            atomicMin(&vals[slot], (unsigned int)i);
            return;
        }
        slot = (slot + 1) & ht_mask;
    }
}

// Fused match + loss: ONE thread per radar point.
// 9 two-word bitmap windows -> 27-bit hitmask -> priority pick (exact
// first-occurrence argmin over (dL1, k)) -> rare hash lookup for the winner row
// -> loss terms -> hierarchical reduction.
__global__ __launch_bounds__(256) void fused_kernel(
        const float* __restrict__ pred_feat,
        const float* __restrict__ pred_occ,
        const float* __restrict__ lidar_feat,
        const int* __restrict__ radar_idx,
        const uint32_t* __restrict__ bitmap,
        const int* __restrict__ keys, const unsigned int* __restrict__ vals,
        uint32_t ht_mask, int ht_log,
        int Nr, float* __restrict__ acc) {
    float occ_a = 0.f, off_a = 0.f, feat_a = 0.f, cnt_a = 0.f;
    int r = blockIdx.x * blockDim.x + threadIdx.x;
    if (r < Nr) {
        int4 ri = reinterpret_cast<const int4*>(radar_idx)[r];
        const int b = ri.x, z = ri.y, y = ri.z, x = ri.w;

        // gather 27 occupancy bits: 9 rows x (two u32 words)
        const int xm1 = max(x - 1, 0);
        const int w0  = xm1 >> 5;
        const int w1  = min(w0 + 1, ROW_WORDS - 1);
        const int base = w0 << 5;
        uint32_t hitmask = 0;
        #pragma unroll
        for (int dz = -1; dz <= 1; ++dz) {
            int zz = min(max(z + dz, 0), Z_ - 1);
            #pragma unroll
            for (int dy = -1; dy <= 1; ++dy) {
                int yy = min(max(y + dy, 0), Y_ - 1);
                uint32_t rw = (uint32_t)((b * Z_ + zz) * Y_ + yy) * ROW_WORDS;
                uint64_t win = (uint64_t)bitmap[rw + w0] |
                               ((uint64_t)bitmap[rw + w1] << 32);
                #pragma unroll
                for (int dx = -1; dx <= 1; ++dx) {
                    int xx = min(max(x + dx, 0), X_ - 1);
                    int k  = (dz + 1) * 9 + (dy + 1) * 3 + (dx + 1);
                    hitmask |= (uint32_t)((win >> (xx - base)) & 1ull) << k;
                }
            }
        }

        // priority pick: group by dL1 ascending; within group ctz == smallest k
        int wk;
        uint32_t g;
        if (hitmask & M0)             wk = 13;
        else if ((g = hitmask & M1))  wk = __builtin_ctz(g);
        else if ((g = hitmask & M2))  wk = __builtin_ctz(g);
        else if ((g = hitmask & M3))  wk = __builtin_ctz(g);
        else                          wk = -1;

        float o = pred_occ[r];
        float sp = fmaxf(o, 0.f) + log1pf(expf(-fabsf(o)));  // stable softplus
        occ_a = sp - ((wk >= 0) ? o : 0.f);

        if (wk >= 0) {
            cnt_a = 1.f;
            int wdz = wk / 9 - 1, wrem = wk % 9;
            int wdy = wrem / 3 - 1, wdx = wrem % 3 - 1;
            int zz = min(max(z + wdz, 0), Z_ - 1);
            int yy = min(max(y + wdy, 0), Y_ - 1);
            int xx = min(max(x + wdx, 0), X_ - 1);
            int key = ((b * Z_ + zz) * Y_ + yy) * X_ + xx;
            // bitmap guarantees presence; probe until found
            uint32_t slot = ht_slot0(key, ht_log);
            int row = 0;
            for (;;) {
                int k2 = keys[slot];
                if (k2 == key) { row = (int)vals[slot]; break; }
                if (k2 == -1)  break;  // unreachable; safety
                slot = (slot + 1) & ht_mask;
            }
            float4 pf = reinterpret_cast<const float4*>(pred_feat)[r];
            float p[3] = { pf.x, pf.y, pf.z };
            float gt[3] = { (float)(zz - z), (float)(yy - y), (float)(xx - x) };
            #pragma unroll
            for (int j = 0; j < 3; ++j) {
                float dd = p[j] - gt[j];
                float ad = fabsf(dd);
                off_a += (ad < 1.f) ? 0.5f * dd * dd : ad - 0.5f;
            }
            feat_a = fabsf(pf.w - lidar_feat[16 * row]);
        }
    }

    // wave-64 butterfly, then LDS block reduce, then 4 atomics per block
    #pragma unroll
    for (int o = 32; o >= 1; o >>= 1) {
        occ_a  += __shfl_xor(occ_a,  o, 64);
        off_a  += __shfl_xor(off_a,  o, 64);
        feat_a += __shfl_xor(feat_a, o, 64);
        cnt_a  += __shfl_xor(cnt_a,  o, 64);
    }
    __shared__ float red[4][4];
    int wid = threadIdx.x >> 6;
    if ((threadIdx.x & 63) == 0) {
        red[wid][0] = occ_a; red[wid][1] = off_a;
        red[wid][2] = feat_a; red[wid][3] = cnt_a;
    }
    __syncthreads();
    if (threadIdx.x == 0) {
        float s0 = 0.f, s1 = 0.f, s2 = 0.f, s3 = 0.f;
        #pragma unroll
        for (int w = 0; w < 4; ++w) {
            s0 += red[w][0]; s1 += red[w][1]; s2 += red[w][2]; s3 += red[w][3];
        }
        atomicAdd(&acc[0],  s0);
        atomicAdd(&acc[16], s1);
        atomicAdd(&acc[32], s2);
        atomicAdd(&acc[48], s3);
    }
}

__global__ void finalize_kernel(const float* __restrict__ acc, int Nr, float* __restrict__ out) {
    float occ  = acc[0] / (float)Nr;
    float cnt  = acc[48];
    float offl = acc[16] / fmaxf(cnt * 3.f, 1.f);
    float feat = acc[32] / fmaxf(cnt, 1.f);
    out[0] = 0.2f * occ + offl + feat;
}

extern "C" void kernel_launch(void* const* d_in, const int* in_sizes, int n_in,
                              void* d_out, int out_size, void* d_ws, size_t ws_size,
                              hipStream_t stream) {
    const float* pred_feat  = (const float*)d_in[0];
    const float* pred_occ   = (const float*)d_in[1];
    const float* lidar_feat = (const float*)d_in[2];
    const int*   radar_idx  = (const int*)d_in[3];
    const int*   lidar_idx  = (const int*)d_in[4];
    int Nr = in_sizes[1];        // pred_occ is (Nr, 1)
    int Nl = in_sizes[2] / 16;   // lidar_features is (Nl, 16)

    const size_t bitmap_bytes = BITMAP_WORDS * 4;        // 4 MiB
    // hash sizing: 256 + bitmap + 8*S must fit ws
    int ht_log = 20;
    while (ht_log > 15 &&
           (size_t)(256 + bitmap_bytes + 8ull * (1ull << ht_log)) > ws_size)
        --ht_log;
    uint32_t ht_size = 1u << ht_log;
    uint32_t ht_mask = ht_size - 1;

    float*        acc    = (float*)d_ws;
    uint32_t*     bitmap = (uint32_t*)((char*)d_ws + 256);
    int*          keys   = (int*)((char*)d_ws + 256 + bitmap_bytes);
    unsigned int* vals   = (unsigned int*)(keys + ht_size);

    // two memsets: {acc+bitmap}=0x00 (contiguous), {keys+vals}=0xFF (contiguous)
    hipMemsetAsync(acc,  0x00, 256 + bitmap_bytes, stream);
    hipMemsetAsync(keys, 0xFF, 8ull * ht_size,     stream);

    hipLaunchKernelGGL(build_kernel, dim3((Nl + 255) / 256), dim3(256), 0, stream,
                       lidar_idx, Nl, bitmap, keys, vals, ht_mask, ht_log);
    hipLaunchKernelGGL(fused_kernel, dim3((Nr + 255) / 256), dim3(256), 0, stream,
                       pred_feat, pred_occ, lidar_feat, radar_idx,
                       bitmap, keys, vals, ht_mask, ht_log, Nr, acc);
    hipLaunchKernelGGL(finalize_kernel, dim3(1), dim3(1), 0, stream, acc, Nr, (float*)d_out);
}

// Round 5
// 109.099 us; speedup vs baseline: 2.8010x; 1.0271x over previous
//
#include <hip/hip_runtime.h>
#include <cstdint>
#include <climits>

// Problem constants (from reference): B=4, Z=32, Y=512, X=512, R=1, C=16
static constexpr int Z_ = 32, Y_ = 512, X_ = 512;
static constexpr int ROW_WORDS = X_ / 32;                  // 16 u32 words per (b,z,y) row
static constexpr size_t NVOX = 4ull * Z_ * Y_ * X_;        // 33,554,432 voxels (2^25)
static constexpr size_t BITMAP_WORDS = NVOX / 32;          // 1M words = 4 MiB
static constexpr unsigned long long EMPTY64 = ~0ull;

__device__ __forceinline__ uint32_t ht_slot0(int key, int ht_log) {
    return ((uint32_t)key * 2654435761u) >> (32 - ht_log);
}

// dL1 priority masks over k = (dz+1)*9 + (dy+1)*3 + (dx+1), k in [0,27)
static constexpr uint32_t M0 = 1u << 13;
static constexpr uint32_t M1 = (1u<<4)|(1u<<10)|(1u<<12)|(1u<<14)|(1u<<16)|(1u<<22);
static constexpr uint32_t M3 = (1u<<0)|(1u<<2)|(1u<<6)|(1u<<8)|(1u<<18)|(1u<<20)|(1u<<24)|(1u<<26);
static constexpr uint32_t MALL = (1u<<27) - 1;
static constexpr uint32_t M2 = MALL & ~(M0|M1|M3);

// ws layout (bytemap path):
//   [0,256) acc | [256, +33.5MB) bytemap | [.., +4MB) bitmap | [.., +8*S) packed table
// fallback path (small ws): [0,256) acc | [256, +4MB) bitmap | [.., +8*S) packed table

// Insert = ONE atomicCAS typically. Entry = (key<<19)|row; same-key duplicates
// resolve via atomicMin on the packed word (key in high bits => min picks min row,
// exactly the stable-argsort + searchsorted-left semantics).
template<int USE_BYTEMAP>
__global__ void build_kernel(const int* __restrict__ lidar_idx, int Nl,
                             unsigned long long* __restrict__ tbl,
                             uint32_t* __restrict__ bitmap,
                             uint8_t* __restrict__ bytemap,
                             uint32_t ht_mask, int ht_log) {
    int i = blockIdx.x * blockDim.x + threadIdx.x;
    if (i >= Nl) return;
    int4 li = reinterpret_cast<const int4*>(lidar_idx)[i];
    int key = ((li.x * Z_ + li.y) * Y_ + li.z) * X_ + li.w;
    if (USE_BYTEMAP) bytemap[key] = 1;   // idempotent plain store, no RMW round-trip
    unsigned long long ins = ((unsigned long long)(uint32_t)key << 19) | (unsigned)i;
    uint32_t slot = ht_slot0(key, ht_log);
    for (;;) {
        unsigned long long prev = atomicCAS(&tbl[slot], EMPTY64, ins);
        if (prev == EMPTY64) {
            if (!USE_BYTEMAP)
                atomicOr(&bitmap[(uint32_t)key >> 5], 1u << (key & 31));
            return;
        }
        if ((prev >> 19) == (unsigned long long)(uint32_t)key) {
            atomicMin(&tbl[slot], ins);   // rare: same-voxel duplicate
            return;
        }
        slot = (slot + 1) & ht_mask;
    }
}

// bytemap (33.5MB) -> bitmap (4MB), fully coalesced, zero atomics.
__global__ __launch_bounds__(256) void compress_kernel(
        const uint8_t* __restrict__ bytemap, uint32_t* __restrict__ bitmap) {
    uint32_t t = blockIdx.x * blockDim.x + threadIdx.x;
    if (t >= BITMAP_WORDS) return;
    const uint4* p = reinterpret_cast<const uint4*>(bytemap) + 2 * t;
    uint4 a = p[0], b = p[1];
    uint32_t cs[8] = { a.x, a.y, a.z, a.w, b.x, b.y, b.z, b.w };
    uint32_t w = 0;
    #pragma unroll
    for (int j = 0; j < 8; ++j) {
        uint32_t c = cs[j];
        w |= (c & 1u)          << (4*j);
        w |= ((c >> 8)  & 1u)  << (4*j + 1);
        w |= ((c >> 16) & 1u)  << (4*j + 2);
        w |= ((c >> 24) & 1u)  << (4*j + 3);
    }
    bitmap[t] = w;
}

// Fused match + loss: one thread per radar point.
// 9 two-word bitmap windows -> 27-bit hitmask -> priority pick (exact
// first-occurrence argmin over (dL1,k)) -> single u64 table probe for winner row.
__global__ __launch_bounds__(256) void fused_kernel(
        const float* __restrict__ pred_feat,
        const float* __restrict__ pred_occ,
        const float* __restrict__ lidar_feat,
        const int* __restrict__ radar_idx,
        const uint32_t* __restrict__ bitmap,
        const unsigned long long* __restrict__ tbl,
        uint32_t ht_mask, int ht_log,
        int Nr, float* __restrict__ acc) {
    float occ_a = 0.f, off_a = 0.f, feat_a = 0.f, cnt_a = 0.f;
    int r = blockIdx.x * blockDim.x + threadIdx.x;
    if (r < Nr) {
        int4 ri = reinterpret_cast<const int4*>(radar_idx)[r];
        const int b = ri.x, z = ri.y, y = ri.z, x = ri.w;

        const int xm1 = max(x - 1, 0);
        const int w0  = xm1 >> 5;
        const int w1  = min(w0 + 1, ROW_WORDS - 1);
        const int base = w0 << 5;
        uint32_t hitmask = 0;
        #pragma unroll
        for (int dz = -1; dz <= 1; ++dz) {
            int zz = min(max(z + dz, 0), Z_ - 1);
            #pragma unroll
            for (int dy = -1; dy <= 1; ++dy) {
                int yy = min(max(y + dy, 0), Y_ - 1);
                uint32_t rw = (uint32_t)((b * Z_ + zz) * Y_ + yy) * ROW_WORDS;
                uint64_t win = (uint64_t)bitmap[rw + w0] |
                               ((uint64_t)bitmap[rw + w1] << 32);
                #pragma unroll
                for (int dx = -1; dx <= 1; ++dx) {
                    int xx = min(max(x + dx, 0), X_ - 1);
                    int k  = (dz + 1) * 9 + (dy + 1) * 3 + (dx + 1);
                    hitmask |= (uint32_t)((win >> (xx - base)) & 1ull) << k;
                }
            }
        }

        int wk;
        uint32_t g;
        if (hitmask & M0)             wk = 13;
        else if ((g = hitmask & M1))  wk = __builtin_ctz(g);
        else if ((g = hitmask & M2))  wk = __builtin_ctz(g);
        else if ((g = hitmask & M3))  wk = __builtin_ctz(g);
        else                          wk = -1;

        float o = pred_occ[r];
        float sp = fmaxf(o, 0.f) + log1pf(expf(-fabsf(o)));  // stable softplus
        occ_a = sp - ((wk >= 0) ? o : 0.f);

        if (wk >= 0) {
            cnt_a = 1.f;
            int wdz = wk / 9 - 1, wrem = wk % 9;
            int wdy = wrem / 3 - 1, wdx = wrem % 3 - 1;
            int zz = min(max(z + wdz, 0), Z_ - 1);
            int yy = min(max(y + wdy, 0), Y_ - 1);
            int xx = min(max(x + wdx, 0), X_ - 1);
            int key = ((b * Z_ + zz) * Y_ + yy) * X_ + xx;
            uint32_t slot = ht_slot0(key, ht_log);
            int row = 0;
            for (;;) {
                unsigned long long v = tbl[slot];
                if ((v >> 19) == (unsigned long long)(uint32_t)key) {
                    row = (int)(v & 0x7FFFFull);
                    break;
                }
                if (v == EMPTY64) break;  // unreachable (bitmap says present); safety
                slot = (slot + 1) & ht_mask;
            }
            float4 pf = reinterpret_cast<const float4*>(pred_feat)[r];
            float p[3]  = { pf.x, pf.y, pf.z };
            float gt[3] = { (float)(zz - z), (float)(yy - y), (float)(xx - x) };
            #pragma unroll
            for (int j = 0; j < 3; ++j) {
                float dd = p[j] - gt[j];
                float ad = fabsf(dd);
                off_a += (ad < 1.f) ? 0.5f * dd * dd : ad - 0.5f;
            }
            feat_a = fabsf(pf.w - lidar_feat[16 * row]);
        }
    }

    #pragma unroll
    for (int o = 32; o >= 1; o >>= 1) {
        occ_a  += __shfl_xor(occ_a,  o, 64);
        off_a  += __shfl_xor(off_a,  o, 64);
        feat_a += __shfl_xor(feat_a, o, 64);
        cnt_a  += __shfl_xor(cnt_a,  o, 64);
    }
    __shared__ float red[4][4];
    int wid = threadIdx.x >> 6;
    if ((threadIdx.x & 63) == 0) {
        red[wid][0] = occ_a; red[wid][1] = off_a;
        red[wid][2] = feat_a; red[wid][3] = cnt_a;
    }
    __syncthreads();
    if (threadIdx.x == 0) {
        float s0 = 0.f, s1 = 0.f, s2 = 0.f, s3 = 0.f;
        #pragma unroll
        for (int w = 0; w < 4; ++w) {
            s0 += red[w][0]; s1 += red[w][1]; s2 += red[w][2]; s3 += red[w][3];
        }
        atomicAdd(&acc[0],  s0);
        atomicAdd(&acc[16], s1);
        atomicAdd(&acc[32], s2);
        atomicAdd(&acc[48], s3);
    }
}

__global__ void finalize_kernel(const float* __restrict__ acc, int Nr, float* __restrict__ out) {
    float occ  = acc[0] / (float)Nr;
    float cnt  = acc[48];
    float offl = acc[16] / fmaxf(cnt * 3.f, 1.f);
    float feat = acc[32] / fmaxf(cnt, 1.f);
    out[0] = 0.2f * occ + offl + feat;
}

extern "C" void kernel_launch(void* const* d_in, const int* in_sizes, int n_in,
                              void* d_out, int out_size, void* d_ws, size_t ws_size,
                              hipStream_t stream) {
    const float* pred_feat  = (const float*)d_in[0];
    const float* pred_occ   = (const float*)d_in[1];
    const float* lidar_feat = (const float*)d_in[2];
    const int*   radar_idx  = (const int*)d_in[3];
    const int*   lidar_idx  = (const int*)d_in[4];
    int Nr = in_sizes[1];        // pred_occ is (Nr, 1)
    int Nl = in_sizes[2] / 16;   // lidar_features is (Nl, 16)

    const size_t bitmap_bytes = BITMAP_WORDS * 4;  // 4 MiB
    int ht_log = 20;
    const size_t tbl_bytes = 8ull << ht_log;       // 8 MiB packed u64 table

    // bytemap path needs 256 + NVOX + 4MB + 8MB ~= 45.9 MB of ws
    bool use_bytemap = ws_size >= 256 + NVOX + bitmap_bytes + tbl_bytes;

    float* acc = (float*)d_ws;
    uint8_t*  bytemap;
    uint32_t* bitmap;
    unsigned long long* tbl;
    if (use_bytemap) {
        bytemap = (uint8_t*)d_ws + 256;
        bitmap  = (uint32_t*)((char*)d_ws + 256 + NVOX);
        tbl     = (unsigned long long*)((char*)d_ws + 256 + NVOX + bitmap_bytes);
        hipMemsetAsync(d_ws, 0x00, 256 + NVOX, stream);        // acc + bytemap
        hipMemsetAsync(tbl,  0xFF, tbl_bytes,  stream);        // EMPTY64
    } else {
        // fallback: no bytemap; build sets bitmap bits with atomicOr
        while (ht_log > 19 &&
               (size_t)(256 + bitmap_bytes + (8ull << ht_log)) > ws_size) --ht_log;
        bytemap = nullptr;
        bitmap  = (uint32_t*)((char*)d_ws + 256);
        tbl     = (unsigned long long*)((char*)d_ws + 256 + bitmap_bytes);
        hipMemsetAsync(d_ws, 0x00, 256 + bitmap_bytes,   stream);
        hipMemsetAsync(tbl,  0xFF, 8ull << ht_log,       stream);
    }
    uint32_t ht_mask = (1u << ht_log) - 1;

    if (use_bytemap) {
        hipLaunchKernelGGL((build_kernel<1>), dim3((Nl + 255) / 256), dim3(256), 0, stream,
                           lidar_idx, Nl, tbl, bitmap, bytemap, ht_mask, ht_log);
        hipLaunchKernelGGL(compress_kernel, dim3((int)(BITMAP_WORDS + 255) / 256), dim3(256),
                           0, stream, bytemap, bitmap);
    } else {
        hipLaunchKernelGGL((build_kernel<0>), dim3((Nl + 255) / 256), dim3(256), 0, stream,
                           lidar_idx, Nl, tbl, bitmap, bytemap, ht_mask, ht_log);
    }
    hipLaunchKernelGGL(fused_kernel, dim3((Nr + 255) / 256), dim3(256), 0, stream,
                       pred_feat, pred_occ, lidar_feat, radar_idx,
                       bitmap, tbl, ht_mask, ht_log, Nr, acc);
    hipLaunchKernelGGL(finalize_kernel, dim3(1), dim3(1), 0, stream, acc, Nr, (float*)d_out);
}

// Round 6
// 104.363 us; speedup vs baseline: 2.9281x; 1.0454x over previous
//
#include <hip/hip_runtime.h>
#include <cstdint>
#include <climits>

// Problem constants (from reference): B=4, Z=32, Y=512, X=512, R=1, C=16
static constexpr int Z_ = 32, Y_ = 512, X_ = 512;
static constexpr int ROW_WORDS = X_ / 32;                  // 16 u32 words per (b,z,y) row
static constexpr size_t NVOX = 4ull * Z_ * Y_ * X_;        // 33,554,432 voxels (2^25)
static constexpr size_t BITMAP_WORDS = NVOX / 32;          // 1M words = 4 MiB
static constexpr unsigned long long EMPTY64 = ~0ull;

__device__ __forceinline__ uint32_t ht_slot0(int key, int ht_log) {
    return ((uint32_t)key * 2654435761u) >> (32 - ht_log);
}

// dL1 priority masks over k = (dz+1)*9 + (dy+1)*3 + (dx+1), k in [0,27)
static constexpr uint32_t M0 = 1u << 13;
static constexpr uint32_t M1 = (1u<<4)|(1u<<10)|(1u<<12)|(1u<<14)|(1u<<16)|(1u<<22);
static constexpr uint32_t M3 = (1u<<0)|(1u<<2)|(1u<<6)|(1u<<8)|(1u<<18)|(1u<<20)|(1u<<24)|(1u<<26);
static constexpr uint32_t MALL = (1u<<27) - 1;
static constexpr uint32_t M2 = MALL & ~(M0|M1|M3);

// ws layout:
//   [0, 256)        : acc[0..3] at 64B stride (occ, off, feat, cnt)
//   [256, +4MiB)    : occupancy bitmap (1 bit per voxel) — L2-resident, atomicOr
//   [.., +8*S)      : packed u64 table: (key<<19)|row, EMPTY64 = empty

// Insert = ONE scattered atomicCAS per point (the cost driver); the bitmap
// atomicOr is L2-resident (4 MiB footprint, ~6 sets/line) and nearly free.
// Same-key duplicates resolve via atomicMin on the packed word (key in high
// bits => min picks min row == stable-argsort + searchsorted-left semantics).
__global__ void build_kernel(const int* __restrict__ lidar_idx, int Nl,
                             unsigned long long* __restrict__ tbl,
                             uint32_t* __restrict__ bitmap,
                             uint32_t ht_mask, int ht_log) {
    int i = blockIdx.x * blockDim.x + threadIdx.x;
    if (i >= Nl) return;
    int4 li = reinterpret_cast<const int4*>(lidar_idx)[i];
    int key = ((li.x * Z_ + li.y) * Y_ + li.z) * X_ + li.w;
    unsigned long long ins = ((unsigned long long)(uint32_t)key << 19) | (unsigned)i;
    uint32_t slot = ht_slot0(key, ht_log);
    for (;;) {
        unsigned long long prev = atomicCAS(&tbl[slot], EMPTY64, ins);
        if (prev == EMPTY64) {
            // first claimant publishes the presence bit (L2-resident RMW)
            atomicOr(&bitmap[(uint32_t)key >> 5], 1u << (key & 31));
            return;
        }
        if ((prev >> 19) == (unsigned long long)(uint32_t)key) {
            atomicMin(&tbl[slot], ins);   // rare: same-voxel duplicate
            return;
        }
        slot = (slot + 1) & ht_mask;
    }
}

// Fused match + loss: one thread per radar point.
// 9 two-word bitmap windows -> 27-bit hitmask -> priority pick (exact
// first-occurrence argmin over (dL1,k)) -> single u64 table probe for winner row.
__global__ __launch_bounds__(256) void fused_kernel(
        const float* __restrict__ pred_feat,
        const float* __restrict__ pred_occ,
        const float* __restrict__ lidar_feat,
        const int* __restrict__ radar_idx,
        const uint32_t* __restrict__ bitmap,
        const unsigned long long* __restrict__ tbl,
        uint32_t ht_mask, int ht_log,
        int Nr, float* __restrict__ acc) {
    float occ_a = 0.f, off_a = 0.f, feat_a = 0.f, cnt_a = 0.f;
    int r = blockIdx.x * blockDim.x + threadIdx.x;
    if (r < Nr) {
        int4 ri = reinterpret_cast<const int4*>(radar_idx)[r];
        const int b = ri.x, z = ri.y, y = ri.z, x = ri.w;

        const int xm1 = max(x - 1, 0);
        const int w0  = xm1 >> 5;
        const int w1  = min(w0 + 1, ROW_WORDS - 1);
        const int base = w0 << 5;
        uint32_t hitmask = 0;
        #pragma unroll
        for (int dz = -1; dz <= 1; ++dz) {
            int zz = min(max(z + dz, 0), Z_ - 1);
            #pragma unroll
            for (int dy = -1; dy <= 1; ++dy) {
                int yy = min(max(y + dy, 0), Y_ - 1);
                uint32_t rw = (uint32_t)((b * Z_ + zz) * Y_ + yy) * ROW_WORDS;
                uint64_t win = (uint64_t)bitmap[rw + w0] |
                               ((uint64_t)bitmap[rw + w1] << 32);
                #pragma unroll
                for (int dx = -1; dx <= 1; ++dx) {
                    int xx = min(max(x + dx, 0), X_ - 1);
                    int k  = (dz + 1) * 9 + (dy + 1) * 3 + (dx + 1);
                    hitmask |= (uint32_t)((win >> (xx - base)) & 1ull) << k;
                }
            }
        }

        int wk;
        uint32_t g;
        if (hitmask & M0)             wk = 13;
        else if ((g = hitmask & M1))  wk = __builtin_ctz(g);
        else if ((g = hitmask & M2))  wk = __builtin_ctz(g);
        else if ((g = hitmask & M3))  wk = __builtin_ctz(g);
        else                          wk = -1;

        float o = pred_occ[r];
        float sp = fmaxf(o, 0.f) + log1pf(expf(-fabsf(o)));  // stable softplus
        occ_a = sp - ((wk >= 0) ? o : 0.f);

        if (wk >= 0) {
            cnt_a = 1.f;
            int wdz = wk / 9 - 1, wrem = wk % 9;
            int wdy = wrem / 3 - 1, wdx = wrem % 3 - 1;
            int zz = min(max(z + wdz, 0), Z_ - 1);
            int yy = min(max(y + wdy, 0), Y_ - 1);
            int xx = min(max(x + wdx, 0), X_ - 1);
            int key = ((b * Z_ + zz) * Y_ + yy) * X_ + xx;
            uint32_t slot = ht_slot0(key, ht_log);
            int row = 0;
            for (;;) {
                unsigned long long v = tbl[slot];
                if ((v >> 19) == (unsigned long long)(uint32_t)key) {
                    row = (int)(v & 0x7FFFFull);
                    break;
                }
                if (v == EMPTY64) break;  // unreachable (bitmap says present); safety
                slot = (slot + 1) & ht_mask;
            }
            float4 pf = reinterpret_cast<const float4*>(pred_feat)[r];
            float p[3]  = { pf.x, pf.y, pf.z };
            float gt[3] = { (float)(zz - z), (float)(yy - y), (float)(xx - x) };
            #pragma unroll
            for (int j = 0; j < 3; ++j) {
                float dd = p[j] - gt[j];
                float ad = fabsf(dd);
                off_a += (ad < 1.f) ? 0.5f * dd * dd : ad - 0.5f;
            }
            feat_a = fabsf(pf.w - lidar_feat[16 * row]);
        }
    }

    #pragma unroll
    for (int o = 32; o >= 1; o >>= 1) {
        occ_a  += __shfl_xor(occ_a,  o, 64);
        off_a  += __shfl_xor(off_a,  o, 64);
        feat_a += __shfl_xor(feat_a, o, 64);
        cnt_a  += __shfl_xor(cnt_a,  o, 64);
    }
    __shared__ float red[4][4];
    int wid = threadIdx.x >> 6;
    if ((threadIdx.x & 63) == 0) {
        red[wid][0] = occ_a; red[wid][1] = off_a;
        red[wid][2] = feat_a; red[wid][3] = cnt_a;
    }
    __syncthreads();
    if (threadIdx.x == 0) {
        float s0 = 0.f, s1 = 0.f, s2 = 0.f, s3 = 0.f;
        #pragma unroll
        for (int w = 0; w < 4; ++w) {
            s0 += red[w][0]; s1 += red[w][1]; s2 += red[w][2]; s3 += red[w][3];
        }
        atomicAdd(&acc[0],  s0);
        atomicAdd(&acc[16], s1);
        atomicAdd(&acc[32], s2);
        atomicAdd(&acc[48], s3);
    }
}

__global__ void finalize_kernel(const float* __restrict__ acc, int Nr, float* __restrict__ out) {
    float occ  = acc[0] / (float)Nr;
    float cnt  = acc[48];
    float offl = acc[16] / fmaxf(cnt * 3.f, 1.f);
    float feat = acc[32] / fmaxf(cnt, 1.f);
    out[0] = 0.2f * occ + offl + feat;
}

extern "C" void kernel_launch(void* const* d_in, const int* in_sizes, int n_in,
                              void* d_out, int out_size, void* d_ws, size_t ws_size,
                              hipStream_t stream) {
    const float* pred_feat  = (const float*)d_in[0];
    const float* pred_occ   = (const float*)d_in[1];
    const float* lidar_feat = (const float*)d_in[2];
    const int*   radar_idx  = (const int*)d_in[3];
    const int*   lidar_idx  = (const int*)d_in[4];
    int Nr = in_sizes[1];        // pred_occ is (Nr, 1)
    int Nl = in_sizes[2] / 16;   // lidar_features is (Nl, 16)

    const size_t bitmap_bytes = BITMAP_WORDS * 4;  // 4 MiB
    int ht_log = 20;
    while (ht_log > 19 &&
           (size_t)(256 + bitmap_bytes + (8ull << ht_log)) > ws_size) --ht_log;
    uint32_t ht_mask = (1u << ht_log) - 1;

    float*              acc    = (float*)d_ws;
    uint32_t*           bitmap = (uint32_t*)((char*)d_ws + 256);
    unsigned long long* tbl    = (unsigned long long*)((char*)d_ws + 256 + bitmap_bytes);

    hipMemsetAsync(d_ws, 0x00, 256 + bitmap_bytes, stream);  // acc + bitmap
    hipMemsetAsync(tbl,  0xFF, 8ull << ht_log,     stream);  // EMPTY64

    hipLaunchKernelGGL(build_kernel, dim3((Nl + 255) / 256), dim3(256), 0, stream,
                       lidar_idx, Nl, tbl, bitmap, ht_mask, ht_log);
    hipLaunchKernelGGL(fused_kernel, dim3((Nr + 255) / 256), dim3(256), 0, stream,
                       pred_feat, pred_occ, lidar_feat, radar_idx,
                       bitmap, tbl, ht_mask, ht_log, Nr, acc);
    hipLaunchKernelGGL(finalize_kernel, dim3(1), dim3(1), 0, stream, acc, Nr, (float*)d_out);
}

// Round 7
// 100.108 us; speedup vs baseline: 3.0526x; 1.0425x over previous
//
#include <hip/hip_runtime.h>
#include <cstdint>

// Problem constants (from reference): B=4, Z=32, Y=512, X=512, R=1, C=16
static constexpr int Z_ = 32, Y_ = 512, X_ = 512;
static constexpr int ROW_WORDS = X_ / 32;                  // 16 u32 words per (b,z,y) row
static constexpr size_t NVOX = 4ull * Z_ * Y_ * X_;        // 33,554,432 voxels (2^25)
static constexpr size_t BITMAP_WORDS = NVOX / 32;          // 1M words = 4 MiB
static constexpr int KT_LOG = 19;                          // 524288 slots for <=200k radar voxels
static constexpr uint32_t KT_SIZE = 1u << KT_LOG;
static constexpr uint32_t KT_MASK = KT_SIZE - 1;
static constexpr uint32_t EMPTY32 = 0xFFFFFFFFu;           // keys < 2^25, so invalid
static constexpr uint32_t REC_SENTINEL = 0xFFFFFFFFu;      // packed < 2^26, so invalid

__device__ __forceinline__ uint32_t kt_slot0(uint32_t key) {
    return (key * 2654435761u) >> (32 - KT_LOG);
}

// ws layout:
//   [0, 256)        : acc[0..3] at 64B stride (occ, off, feat, cnt)
//   [256, +4MiB)    : RADAR occupancy bitmap (1 bit per voxel)
//   [.., +2MiB)     : keytab (u32 voxel key per slot, EMPTY32 = empty)
//   [.., +2MiB)     : records (u32 packed (dL1<<24)|(k<<19)|lidar_row, REC_SENTINEL = no match)

// One CAS + one (independent, idempotent) bitmap Or per radar point.
// 200k radar points => ~400k memory-side ops, half of the lidar-side build.
__global__ void radar_build(const int* __restrict__ radar_idx, int Nr,
                            uint32_t* __restrict__ keytab,
                            uint32_t* __restrict__ bitmap) {
    int i = blockIdx.x * blockDim.x + threadIdx.x;
    if (i >= Nr) return;
    int4 ri = reinterpret_cast<const int4*>(radar_idx)[i];
    uint32_t key = (uint32_t)(((ri.x * Z_ + ri.y) * Y_ + ri.z) * X_ + ri.w);
    // fire-and-forget presence bit; independent of the CAS below (better MLP)
    atomicOr(&bitmap[key >> 5], 1u << (key & 31));
    uint32_t slot = kt_slot0(key);
    for (;;) {
        uint32_t prev = atomicCAS(&keytab[slot], EMPTY32, key);
        if (prev == EMPTY32 || prev == key) return;  // claimed (value IS the key)
        slot = (slot + 1) & KT_MASK;
    }
}

// Lidar pass: each lidar point finds radar voxels in its 27-neighborhood
// (strict in-domain scan, NO clamping: delta must be the true L - R) and
// atomicMins packed (dL1<<24)|(k<<19)|row into that radar voxel's record.
// k = 26 - m where m is the lidar-centered window index: k(L-R) == 26 - m.
// Lexicographic min over (dL1, k, row) == reference first-occurrence argmin
// + min-lidar-row duplicate rule.
__global__ __launch_bounds__(256) void lidar_pass(
        const int* __restrict__ lidar_idx, int Nl,
        const uint32_t* __restrict__ bitmap,
        const uint32_t* __restrict__ keytab,
        uint32_t* __restrict__ records) {
    int i = blockIdx.x * blockDim.x + threadIdx.x;
    if (i >= Nl) return;
    int4 li = reinterpret_cast<const int4*>(lidar_idx)[i];
    const int b = li.x, z = li.y, y = li.z, x = li.w;

    const int xm1 = max(x - 1, 0);
    const int w0  = xm1 >> 5;
    const int w1  = min(w0 + 1, ROW_WORDS - 1);
    const int base = w0 << 5;

    uint32_t mask = 0;  // bit m set => radar voxel present at window offset m
    #pragma unroll
    for (int dz = -1; dz <= 1; ++dz) {
        int zz = z + dz;
        if (zz < 0 || zz >= Z_) continue;
        #pragma unroll
        for (int dy = -1; dy <= 1; ++dy) {
            int yy = y + dy;
            if (yy < 0 || yy >= Y_) continue;
            uint32_t rw = (uint32_t)((b * Z_ + zz) * Y_ + yy) * ROW_WORDS;
            uint64_t win = (uint64_t)bitmap[rw + w0] |
                           ((uint64_t)bitmap[rw + w1] << 32);
            #pragma unroll
            for (int dx = -1; dx <= 1; ++dx) {
                int xx = x + dx;
                if (xx < 0 || xx >= X_) continue;
                int m = (dz + 1) * 9 + (dy + 1) * 3 + (dx + 1);
                mask |= (uint32_t)((win >> (xx - base)) & 1ull) << m;
            }
        }
    }

    while (mask) {
        int m = __builtin_ctz(mask);
        mask &= mask - 1;
        int mdz = m / 9 - 1, mr = m % 9;
        int mdy = mr / 3 - 1, mdx = mr % 3 - 1;
        uint32_t vkey = (uint32_t)(((b * Z_ + (z + mdz)) * Y_ + (y + mdy)) * X_ + (x + mdx));
        uint32_t dl1 = (uint32_t)(abs(mdz) + abs(mdy) + abs(mdx));
        uint32_t k   = (uint32_t)(26 - m);               // k of delta = L - R
        uint32_t packed = (dl1 << 24) | (k << 19) | (uint32_t)i;
        uint32_t slot = kt_slot0(vkey);
        for (;;) {
            uint32_t kk = keytab[slot];
            if (kk == vkey) { atomicMin(&records[slot], packed); break; }
            if (kk == EMPTY32) break;  // unreachable (bitmap says present); safety
            slot = (slot + 1) & KT_MASK;
        }
    }
}

// Loss pass: one thread per radar point; probe own voxel (guaranteed present),
// decode record, accumulate loss terms; hierarchical reduction.
__global__ __launch_bounds__(256) void loss_pass(
        const float* __restrict__ pred_feat,
        const float* __restrict__ pred_occ,
        const float* __restrict__ lidar_feat,
        const int* __restrict__ radar_idx,
        const uint32_t* __restrict__ keytab,
        const uint32_t* __restrict__ records,
        int Nr, float* __restrict__ acc) {
    float occ_a = 0.f, off_a = 0.f, feat_a = 0.f, cnt_a = 0.f;
    int r = blockIdx.x * blockDim.x + threadIdx.x;
    if (r < Nr) {
        int4 ri = reinterpret_cast<const int4*>(radar_idx)[r];
        uint32_t key = (uint32_t)(((ri.x * Z_ + ri.y) * Y_ + ri.z) * X_ + ri.w);
        uint32_t slot = kt_slot0(key);
        uint32_t rec = REC_SENTINEL;
        for (;;) {
            uint32_t kk = keytab[slot];
            if (kk == key) { rec = records[slot]; break; }
            if (kk == EMPTY32) break;  // unreachable; safety
            slot = (slot + 1) & KT_MASK;
        }

        float o = pred_occ[r];
        float sp = fmaxf(o, 0.f) + log1pf(expf(-fabsf(o)));  // stable softplus
        bool matched = (rec != REC_SENTINEL);
        occ_a = sp - (matched ? o : 0.f);

        if (matched) {
            cnt_a = 1.f;
            int wk  = (int)((rec >> 19) & 31u);
            int row = (int)(rec & 0x7FFFFu);
            int wdz = wk / 9 - 1, wr = wk % 9;
            int wdy = wr / 3 - 1, wdx = wr % 3 - 1;
            float4 pf = reinterpret_cast<const float4*>(pred_feat)[r];
            float p[3]  = { pf.x, pf.y, pf.z };
            float gt[3] = { (float)wdz, (float)wdy, (float)wdx };
            #pragma unroll
            for (int j = 0; j < 3; ++j) {
                float dd = p[j] - gt[j];
                float ad = fabsf(dd);
                off_a += (ad < 1.f) ? 0.5f * dd * dd : ad - 0.5f;
            }
            feat_a = fabsf(pf.w - lidar_feat[16 * row]);
        }
    }

    #pragma unroll
    for (int o = 32; o >= 1; o >>= 1) {
        occ_a  += __shfl_xor(occ_a,  o, 64);
        off_a  += __shfl_xor(off_a,  o, 64);
        feat_a += __shfl_xor(feat_a, o, 64);
        cnt_a  += __shfl_xor(cnt_a,  o, 64);
    }
    __shared__ float red[4][4];
    int wid = threadIdx.x >> 6;
    if ((threadIdx.x & 63) == 0) {
        red[wid][0] = occ_a; red[wid][1] = off_a;
        red[wid][2] = feat_a; red[wid][3] = cnt_a;
    }
    __syncthreads();
    if (threadIdx.x == 0) {
        float s0 = 0.f, s1 = 0.f, s2 = 0.f, s3 = 0.f;
        #pragma unroll
        for (int w = 0; w < 4; ++w) {
            s0 += red[w][0]; s1 += red[w][1]; s2 += red[w][2]; s3 += red[w][3];
        }
        atomicAdd(&acc[0],  s0);
        atomicAdd(&acc[16], s1);
        atomicAdd(&acc[32], s2);
        atomicAdd(&acc[48], s3);
    }
}

__global__ void finalize_kernel(const float* __restrict__ acc, int Nr, float* __restrict__ out) {
    float occ  = acc[0] / (float)Nr;
    float cnt  = acc[48];
    float offl = acc[16] / fmaxf(cnt * 3.f, 1.f);
    float feat = acc[32] / fmaxf(cnt, 1.f);
    out[0] = 0.2f * occ + offl + feat;
}

extern "C" void kernel_launch(void* const* d_in, const int* in_sizes, int n_in,
                              void* d_out, int out_size, void* d_ws, size_t ws_size,
                              hipStream_t stream) {
    const float* pred_feat  = (const float*)d_in[0];
    const float* pred_occ   = (const float*)d_in[1];
    const float* lidar_feat = (const float*)d_in[2];
    const int*   radar_idx  = (const int*)d_in[3];
    const int*   lidar_idx  = (const int*)d_in[4];
    int Nr = in_sizes[1];        // pred_occ is (Nr, 1)
    int Nl = in_sizes[2] / 16;   // lidar_features is (Nl, 16)

    const size_t bitmap_bytes = BITMAP_WORDS * 4;   // 4 MiB
    float*    acc     = (float*)d_ws;
    uint32_t* bitmap  = (uint32_t*)((char*)d_ws + 256);
    uint32_t* keytab  = (uint32_t*)((char*)d_ws + 256 + bitmap_bytes);
    uint32_t* records = keytab + KT_SIZE;

    // acc + bitmap -> 0x00 (one call); keytab + records -> 0xFF (one call)
    hipMemsetAsync(d_ws,   0x00, 256 + bitmap_bytes, stream);
    hipMemsetAsync(keytab, 0xFF, 8ull * KT_SIZE,     stream);

    hipLaunchKernelGGL(radar_build, dim3((Nr + 255) / 256), dim3(256), 0, stream,
                       radar_idx, Nr, keytab, bitmap);
    hipLaunchKernelGGL(lidar_pass, dim3((Nl + 255) / 256), dim3(256), 0, stream,
                       lidar_idx, Nl, bitmap, keytab, records);
    hipLaunchKernelGGL(loss_pass, dim3((Nr + 255) / 256), dim3(256), 0, stream,
                       pred_feat, pred_occ, lidar_feat, radar_idx,
                       keytab, records, Nr, acc);
    hipLaunchKernelGGL(finalize_kernel, dim3(1), dim3(1), 0, stream, acc, Nr, (float*)d_out);
}

// Round 8
// 96.217 us; speedup vs baseline: 3.1761x; 1.0404x over previous
//
#include <hip/hip_runtime.h>
#include <cstdint>

// Problem constants (from reference): B=4, Z=32, Y=512, X=512, R=1, C=16
static constexpr int Z_ = 32, Y_ = 512, X_ = 512;
static constexpr int ROW_WORDS = X_ / 32;                  // 16 u32 words per (b,z,y) row
static constexpr size_t NVOX = 4ull * Z_ * Y_ * X_;        // 33,554,432 voxels (2^25)
static constexpr size_t BITMAP_WORDS = NVOX / 32;          // 1M words = 4 MiB
static constexpr int KT_LOG = 19;                          // 524288 slots for <=200k radar voxels
static constexpr uint32_t KT_SIZE = 1u << KT_LOG;
static constexpr uint32_t KT_MASK = KT_SIZE - 1;
static constexpr unsigned long long EMPTY64 = ~0ull;
static constexpr uint32_t REC_SENTINEL = 0xFFFFFFFFu;      // packed < 2^26, so invalid

__device__ __forceinline__ uint32_t kt_slot0(uint32_t key) {
    return (key * 2654435761u) >> (32 - KT_LOG);
}

// ws layout:
//   [0, 256)        : acc[0..3] at 64B stride (occ, off, feat, cnt)
//   [256, +4MiB)    : RADAR occupancy bitmap (1 bit per voxel)
//   [.., +4MiB)     : u64 table: (voxel_key<<32) | record
//                     record = (dL1<<24)|(k<<19)|lidar_row, REC_SENTINEL = no match

// Fast init: rocclr's fillBufferAligned runs at 8% occupancy (~42us for 4MB).
// One grid-stride kernel zeroes acc+bitmap and 0xFF-fills the table in ~2us.
__global__ __launch_bounds__(256) void init_kernel(
        uint4* __restrict__ zero_base, uint32_t n_zero,
        uint4* __restrict__ ff_base, uint32_t n_ff) {
    uint32_t t = blockIdx.x * blockDim.x + threadIdx.x;
    uint32_t stride = gridDim.x * blockDim.x;
    const uint4 z = make_uint4(0u, 0u, 0u, 0u);
    const uint4 f = make_uint4(~0u, ~0u, ~0u, ~0u);
    for (uint32_t i = t; i < n_zero; i += stride) zero_base[i] = z;
    for (uint32_t i = t; i < n_ff; i += stride) ff_base[i] = f;
}

// One u64 CAS + one (independent, idempotent) bitmap Or per radar point.
// Slot claim presets the record to REC_SENTINEL in the same CAS.
__global__ void radar_build(const int* __restrict__ radar_idx, int Nr,
                            unsigned long long* __restrict__ tbl,
                            uint32_t* __restrict__ bitmap) {
    int i = blockIdx.x * blockDim.x + threadIdx.x;
    if (i >= Nr) return;
    int4 ri = reinterpret_cast<const int4*>(radar_idx)[i];
    uint32_t key = (uint32_t)(((ri.x * Z_ + ri.y) * Y_ + ri.z) * X_ + ri.w);
    // fire-and-forget presence bit; independent of the CAS below (better MLP)
    atomicOr(&bitmap[key >> 5], 1u << (key & 31));
    unsigned long long ins = ((unsigned long long)key << 32) | REC_SENTINEL;
    uint32_t slot = kt_slot0(key);
    for (;;) {
        unsigned long long prev = atomicCAS(&tbl[slot], EMPTY64, ins);
        if (prev == EMPTY64 || (uint32_t)(prev >> 32) == key) return;
        slot = (slot + 1) & KT_MASK;
    }
}

// Lidar pass: each lidar point finds radar voxels in its 27-neighborhood
// (strict in-domain scan, NO clamping: delta must be the true L - R) and
// atomicMins (key<<32)|(dL1<<24)|(k<<19)|row into that voxel's u64 entry.
// All contenders for a slot share the same key (high bits equal), so u64 min
// == min over packed record == reference first-occurrence argmin (k = 26-m
// is the k-index of delta L-R) + min-lidar-row duplicate rule.
__global__ __launch_bounds__(256) void lidar_pass(
        const int* __restrict__ lidar_idx, int Nl,
        const uint32_t* __restrict__ bitmap,
        unsigned long long* __restrict__ tbl) {
    int i = blockIdx.x * blockDim.x + threadIdx.x;
    if (i >= Nl) return;
    int4 li = reinterpret_cast<const int4*>(lidar_idx)[i];
    const int b = li.x, z = li.y, y = li.z, x = li.w;

    const int xm1 = max(x - 1, 0);
    const int w0  = xm1 >> 5;
    const int w1  = min(w0 + 1, ROW_WORDS - 1);
    const int base = w0 << 5;

    uint32_t mask = 0;  // bit m set => radar voxel present at window offset m
    #pragma unroll
    for (int dz = -1; dz <= 1; ++dz) {
        int zz = z + dz;
        if (zz < 0 || zz >= Z_) continue;
        #pragma unroll
        for (int dy = -1; dy <= 1; ++dy) {
            int yy = y + dy;
            if (yy < 0 || yy >= Y_) continue;
            uint32_t rw = (uint32_t)((b * Z_ + zz) * Y_ + yy) * ROW_WORDS;
            uint64_t win = (uint64_t)bitmap[rw + w0] |
                           ((uint64_t)bitmap[rw + w1] << 32);
            #pragma unroll
            for (int dx = -1; dx <= 1; ++dx) {
                int xx = x + dx;
                if (xx < 0 || xx >= X_) continue;
                int m = (dz + 1) * 9 + (dy + 1) * 3 + (dx + 1);
                mask |= (uint32_t)((win >> (xx - base)) & 1ull) << m;
            }
        }
    }

    while (mask) {
        int m = __builtin_ctz(mask);
        mask &= mask - 1;
        int mdz = m / 9 - 1, mr = m % 9;
        int mdy = mr / 3 - 1, mdx = mr % 3 - 1;
        uint32_t vkey = (uint32_t)(((b * Z_ + (z + mdz)) * Y_ + (y + mdy)) * X_ + (x + mdx));
        uint32_t dl1 = (uint32_t)(abs(mdz) + abs(mdy) + abs(mdx));
        uint32_t k   = (uint32_t)(26 - m);               // k of delta = L - R
        unsigned long long packed =
            ((unsigned long long)vkey << 32) | (dl1 << 24) | (k << 19) | (uint32_t)i;
        uint32_t slot = kt_slot0(vkey);
        for (;;) {
            unsigned long long v = tbl[slot];
            if ((uint32_t)(v >> 32) == vkey) { atomicMin(&tbl[slot], packed); break; }
            if (v == EMPTY64) break;  // unreachable (bitmap says present); safety
            slot = (slot + 1) & KT_MASK;
        }
    }
}

// Loss pass: one thread per radar point; probe own voxel (guaranteed present),
// decode record, accumulate loss terms; hierarchical reduction.
__global__ __launch_bounds__(256) void loss_pass(
        const float* __restrict__ pred_feat,
        const float* __restrict__ pred_occ,
        const float* __restrict__ lidar_feat,
        const int* __restrict__ radar_idx,
        const unsigned long long* __restrict__ tbl,
        int Nr, float* __restrict__ acc) {
    float occ_a = 0.f, off_a = 0.f, feat_a = 0.f, cnt_a = 0.f;
    int r = blockIdx.x * blockDim.x + threadIdx.x;
    if (r < Nr) {
        int4 ri = reinterpret_cast<const int4*>(radar_idx)[r];
        uint32_t key = (uint32_t)(((ri.x * Z_ + ri.y) * Y_ + ri.z) * X_ + ri.w);
        uint32_t slot = kt_slot0(key);
        uint32_t rec = REC_SENTINEL;
        for (;;) {
            unsigned long long v = tbl[slot];
            if ((uint32_t)(v >> 32) == key) { rec = (uint32_t)v; break; }
            if (v == EMPTY64) break;  // unreachable; safety
            slot = (slot + 1) & KT_MASK;
        }

        float o = pred_occ[r];
        float sp = fmaxf(o, 0.f) + log1pf(expf(-fabsf(o)));  // stable softplus
        bool matched = (rec != REC_SENTINEL);
        occ_a = sp - (matched ? o : 0.f);

        if (matched) {
            cnt_a = 1.f;
            int wk  = (int)((rec >> 19) & 31u);
            int row = (int)(rec & 0x7FFFFu);
            int wdz = wk / 9 - 1, wr = wk % 9;
            int wdy = wr / 3 - 1, wdx = wr % 3 - 1;
            float4 pf = reinterpret_cast<const float4*>(pred_feat)[r];
            float p[3]  = { pf.x, pf.y, pf.z };
            float gt[3] = { (float)wdz, (float)wdy, (float)wdx };
            #pragma unroll
            for (int j = 0; j < 3; ++j) {
                float dd = p[j] - gt[j];
                float ad = fabsf(dd);
                off_a += (ad < 1.f) ? 0.5f * dd * dd : ad - 0.5f;
            }
            feat_a = fabsf(pf.w - lidar_feat[16 * row]);
        }
    }

    #pragma unroll
    for (int o = 32; o >= 1; o >>= 1) {
        occ_a  += __shfl_xor(occ_a,  o, 64);
        off_a  += __shfl_xor(off_a,  o, 64);
        feat_a += __shfl_xor(feat_a, o, 64);
        cnt_a  += __shfl_xor(cnt_a,  o, 64);
    }
    __shared__ float red[4][4];
    int wid = threadIdx.x >> 6;
    if ((threadIdx.x & 63) == 0) {
        red[wid][0] = occ_a; red[wid][1] = off_a;
        red[wid][2] = feat_a; red[wid][3] = cnt_a;
    }
    __syncthreads();
    if (threadIdx.x == 0) {
        float s0 = 0.f, s1 = 0.f, s2 = 0.f, s3 = 0.f;
        #pragma unroll
        for (int w = 0; w < 4; ++w) {
            s0 += red[w][0]; s1 += red[w][1]; s2 += red[w][2]; s3 += red[w][3];
        }
        atomicAdd(&acc[0],  s0);
        atomicAdd(&acc[16], s1);
        atomicAdd(&acc[32], s2);
        atomicAdd(&acc[48], s3);
    }
}

__global__ void finalize_kernel(const float* __restrict__ acc, int Nr, float* __restrict__ out) {
    float occ  = acc[0] / (float)Nr;
    float cnt  = acc[48];
    float offl = acc[16] / fmaxf(cnt * 3.f, 1.f);
    float feat = acc[32] / fmaxf(cnt, 1.f);
    out[0] = 0.2f * occ + offl + feat;
}

extern "C" void kernel_launch(void* const* d_in, const int* in_sizes, int n_in,
                              void* d_out, int out_size, void* d_ws, size_t ws_size,
                              hipStream_t stream) {
    const float* pred_feat  = (const float*)d_in[0];
    const float* pred_occ   = (const float*)d_in[1];
    const float* lidar_feat = (const float*)d_in[2];
    const int*   radar_idx  = (const int*)d_in[3];
    const int*   lidar_idx  = (const int*)d_in[4];
    int Nr = in_sizes[1];        // pred_occ is (Nr, 1)
    int Nl = in_sizes[2] / 16;   // lidar_features is (Nl, 16)

    const size_t bitmap_bytes = BITMAP_WORDS * 4;   // 4 MiB
    float*              acc    = (float*)d_ws;
    uint32_t*           bitmap = (uint32_t*)((char*)d_ws + 256);
    unsigned long long* tbl    = (unsigned long long*)((char*)d_ws + 256 + bitmap_bytes);

    const uint32_t n_zero = (uint32_t)((256 + bitmap_bytes) / 16);  // acc + bitmap
    const uint32_t n_ff   = (uint32_t)((8ull * KT_SIZE) / 16);      // u64 table

    hipLaunchKernelGGL(init_kernel, dim3(1024), dim3(256), 0, stream,
                       (uint4*)d_ws, n_zero, (uint4*)tbl, n_ff);
    hipLaunchKernelGGL(radar_build, dim3((Nr + 255) / 256), dim3(256), 0, stream,
                       radar_idx, Nr, tbl, bitmap);
    hipLaunchKernelGGL(lidar_pass, dim3((Nl + 255) / 256), dim3(256), 0, stream,
                       lidar_idx, Nl, bitmap, tbl);
    hipLaunchKernelGGL(loss_pass, dim3((Nr + 255) / 256), dim3(256), 0, stream,
                       pred_feat, pred_occ, lidar_feat, radar_idx, tbl, Nr, acc);
    hipLaunchKernelGGL(finalize_kernel, dim3(1), dim3(1), 0, stream, acc, Nr, (float*)d_out);
}